// Round 5
// baseline (344.098 us; speedup 1.0000x reference)
//
#include <hip/hip_runtime.h>
#include <hip/hip_fp16.h>

#define NEG_SLOPE 0.2f
#define BK 128            // dst nodes per bucket
#define BK_SHIFT 7
#define CH 8192           // edges per scatter workgroup
#define BMAX 1024         // max buckets (N<=131072)

__device__ __forceinline__ float leaky(float v) { return v > 0.f ? v : NEG_SLOPE * v; }

// ---------------- phase A: global bucket histogram ----------------
__global__ __launch_bounds__(256) void k_hist(const int* __restrict__ ei, int E, int ET,
                                              int B, int* __restrict__ ghist) {
  __shared__ int hist[BMAX];
  int t = threadIdx.x;
  for (int i = t; i < B; i += 256) hist[i] = 0;
  __syncthreads();
  int cbase = blockIdx.x * CH;
  int lim = min(CH, ET - cbase);
  for (int k = t; k < lim; k += 256) {
    int e = cbase + k;
    int d = (e < E) ? ei[E + e] : (e - E);   // self-loops appended
    atomicAdd(&hist[d >> BK_SHIFT], 1);
  }
  __syncthreads();
  for (int i = t; i < B; i += 256)
    if (hist[i]) atomicAdd(&ghist[i], hist[i]);
}

// ---------------- phase B: scan bucket counts -> offsets + cursors ----------------
__global__ __launch_bounds__(256) void k_scanbk(const int* __restrict__ ghist, int B,
                                                int* __restrict__ offs, int* __restrict__ gcur) {
  __shared__ int part[256];
  __shared__ int vals[BMAX];
  int t = threadIdx.x;
  int b4 = t * 4, s = 0;
  for (int i = 0; i < 4; ++i) {
    int idx = b4 + i;
    int v = (idx < B) ? ghist[idx] : 0;
    vals[idx] = v; s += v;
  }
  part[t] = s;
  __syncthreads();
  for (int d = 1; d < 256; d <<= 1) {
    int tv = (t >= d) ? part[t - d] : 0;
    __syncthreads();
    part[t] += tv;
    __syncthreads();
  }
  int run = part[t] - s;   // exclusive prefix of this thread's 4 buckets
  for (int i = 0; i < 4; ++i) {
    int idx = b4 + i;
    if (idx < B) { offs[idx] = run; gcur[idx] = run; }
    run += vals[idx];
  }
}

// ---------------- phase C: LDS-binned scatter (coalesced runs) ----------------
__global__ __launch_bounds__(256) void k_scatter(const int* __restrict__ ei, int E, int ET,
                                                 int B, int* __restrict__ gcur,
                                                 unsigned int* __restrict__ grec) {
  __shared__ int hist[BMAX];
  __shared__ int base[BMAX];
  __shared__ int cur[BMAX];
  __shared__ int gb[BMAX];
  __shared__ int part[256];
  __shared__ unsigned int recs[CH];
  __shared__ unsigned short bOf[CH];
  int t = threadIdx.x;
  for (int i = t; i < B; i += 256) hist[i] = 0;
  __syncthreads();
  int cbase = blockIdx.x * CH;
  int lim = min(CH, ET - cbase);
  // pass 1: local counts
  for (int k = t; k < lim; k += 256) {
    int e = cbase + k;
    int d = (e < E) ? ei[E + e] : (e - E);
    atomicAdd(&hist[d >> BK_SHIFT], 1);
  }
  __syncthreads();
  // scan hist -> base (exclusive), cur = base
  {
    int b4 = t * 4, s = 0;
    int v0 = 0, v1 = 0, v2 = 0, v3 = 0;
    if (b4 + 0 < B) v0 = hist[b4 + 0];
    if (b4 + 1 < B) v1 = hist[b4 + 1];
    if (b4 + 2 < B) v2 = hist[b4 + 2];
    if (b4 + 3 < B) v3 = hist[b4 + 3];
    s = v0 + v1 + v2 + v3;
    part[t] = s;
    __syncthreads();
    for (int d = 1; d < 256; d <<= 1) {
      int tv = (t >= d) ? part[t - d] : 0;
      __syncthreads();
      part[t] += tv;
      __syncthreads();
    }
    int run = part[t] - s;
    if (b4 + 0 < B) { base[b4 + 0] = run; cur[b4 + 0] = run; } run += v0;
    if (b4 + 1 < B) { base[b4 + 1] = run; cur[b4 + 1] = run; } run += v1;
    if (b4 + 2 < B) { base[b4 + 2] = run; cur[b4 + 2] = run; } run += v2;
    if (b4 + 3 < B) { base[b4 + 3] = run; cur[b4 + 3] = run; } run += v3;
  }
  __syncthreads();
  // pass 2: place records into LDS grouped by bucket
  for (int k = t; k < lim; k += 256) {
    int e = cbase + k;
    int s, d;
    if (e < E) { s = ei[e]; d = ei[E + e]; }
    else       { s = e - E; d = s; }
    int b = d >> BK_SHIFT;
    int r = atomicAdd(&cur[b], 1);
    recs[r] = (unsigned)s | ((unsigned)(d & (BK - 1)) << 17);
    bOf[r] = (unsigned short)b;
  }
  __syncthreads();
  // reserve contiguous global regions per bucket
  for (int i = t; i < B; i += 256) {
    int cnt = cur[i] - base[i];
    gb[i] = cnt ? atomicAdd(&gcur[i], cnt) : 0;
  }
  __syncthreads();
  // flush: consecutive LDS slots in a bucket -> consecutive global addresses
  for (int p = t; p < lim; p += 256) {
    int b = bOf[p];
    grec[gb[b] + (p - base[b])] = recs[p];
  }
}

// ---------------- phase D: within-bucket counting sort -> per-dst CSR ----------------
__global__ __launch_bounds__(256) void k_sortbk(const unsigned int* __restrict__ grec,
    const int* __restrict__ offs, const int* __restrict__ ghist,
    int N, int B, int ET, int* __restrict__ csr2, int* __restrict__ offs2) {
  __shared__ int hist[BK];
  __shared__ int cur[BK];
  __shared__ int sc[BK];
  int b = blockIdx.x;
  int t = threadIdx.x;
  if (t < BK) hist[t] = 0;
  __syncthreads();
  int i0 = offs[b], cnt = ghist[b];
  for (int i = t; i < cnt; i += 256) atomicAdd(&hist[grec[i0 + i] >> 17], 1);
  __syncthreads();
  if (t < BK) sc[t] = hist[t];
  __syncthreads();
  for (int d = 1; d < BK; d <<= 1) {
    int v = (t >= d && t < BK) ? sc[t - d] : 0;
    __syncthreads();
    if (t < BK) sc[t] += v;
    __syncthreads();
  }
  if (t < BK) {
    int excl = sc[t] - hist[t];
    cur[t] = excl;
    int n = (b << BK_SHIFT) + t;
    if (n < N) offs2[n] = i0 + excl;
  }
  if (b == 0 && t == 0) offs2[N] = ET;
  __syncthreads();
  for (int i = t; i < cnt; i += 256) {
    unsigned r = grec[i0 + i];
    int dl = r >> 17;
    int p = atomicAdd(&cur[dl], 1);
    csr2[i0 + p] = r & 0x1FFFF;
  }
}

// ---------------- layer math ----------------

// h = x @ W1 (512 -> 16) as fp16, plus alpha_s/alpha_d (f32).
// Block = 256 thr = 4 waves over 64 nodes; wave w owns k in [128w, 128w+128).
// W1 row address is wave-uniform -> scalar loads. LDS reduce (2 barriers).
__global__ __launch_bounds__(256) void k_gemm1(
    const float* __restrict__ x, const float* __restrict__ W1,
    const float* __restrict__ a_s, const float* __restrict__ a_d,
    int N, __half* __restrict__ h, float* __restrict__ asv, float* __restrict__ adv) {
  __shared__ float red[4 * 64 * 17];
  const int tid = threadIdx.x;
  const int lane = tid & 63;
  const int wv = tid >> 6;                 // k-quarter
  const int nbase = blockIdx.x * 64;
  const int node = nbase + lane;

  float acc[16];
#pragma unroll
  for (int j = 0; j < 16; ++j) acc[j] = 0.f;

  if (node < N) {
    const float4* xr = (const float4*)(x + (size_t)node * 512 + wv * 128);
#pragma unroll
    for (int it = 0; it < 4; ++it) {       // 4 x 8 float4 = 128 k-values
      float4 b[8];
#pragma unroll
      for (int u = 0; u < 8; ++u) b[u] = xr[it * 8 + u];
#pragma unroll
      for (int u = 0; u < 8; ++u) {
        float xq[4] = {b[u].x, b[u].y, b[u].z, b[u].w};
#pragma unroll
        for (int q = 0; q < 4; ++q) {
          const float* wrow = W1 + (size_t)(wv * 128 + it * 32 + u * 4 + q) * 16; // uniform
#pragma unroll
          for (int j = 0; j < 16; ++j) acc[j] = fmaf(xq[q], wrow[j], acc[j]);
        }
      }
    }
  }
  float* myrow = red + (wv * 64 + lane) * 17;
#pragma unroll
  for (int j = 0; j < 16; ++j) myrow[j] = acc[j];
  __syncthreads();
  // final: thread t -> node t>>2, j-quad t&3 (4 adjacent lanes per node)
  {
    const int n = tid >> 2, part = tid & 3;
    const int gnode = nbase + n;
    if (gnode < N) {
      float f0 = 0.f, f1 = 0.f, f2 = 0.f, f3 = 0.f;
#pragma unroll
      for (int w = 0; w < 4; ++w) {
        const float* r = red + (w * 64 + n) * 17 + part * 4;
        f0 += r[0]; f1 += r[1]; f2 += r[2]; f3 += r[3];
      }
      union { __half2 h2[2]; uint2 u; } pk;
      pk.h2[0] = __floats2half2_rn(f0, f1);
      pk.h2[1] = __floats2half2_rn(f2, f3);
      *(uint2*)(h + (size_t)gnode * 16 + part * 4) = pk.u;
      float sp = f0 * a_s[part * 4 + 0] + f1 * a_s[part * 4 + 1] +
                 f2 * a_s[part * 4 + 2] + f3 * a_s[part * 4 + 3];
      float dp = f0 * a_d[part * 4 + 0] + f1 * a_d[part * 4 + 1] +
                 f2 * a_d[part * 4 + 2] + f3 * a_d[part * 4 + 3];
      sp += __shfl_xor(sp, 1); sp += __shfl_xor(sp, 2);
      dp += __shfl_xor(dp, 1); dp += __shfl_xor(dp, 2);
      if (part == 0) asv[gnode] = sp;
      if (part == 1) adv[gnode] = dp;
    }
  }
}

// h = xin @ W (16 -> 16) as fp16, plus alpha_s/alpha_d (f32).
__global__ void k_gemm16(const float* __restrict__ xin, const float* __restrict__ W,
                         const float* __restrict__ a_s, const float* __restrict__ a_d,
                         int N, __half* __restrict__ h, float* __restrict__ asv,
                         float* __restrict__ adv) {
  int n = blockIdx.x * blockDim.x + threadIdx.x;
  if (n >= N) return;
  float xr[16];
#pragma unroll
  for (int c = 0; c < 4; ++c) ((float4*)xr)[c] = *(const float4*)(xin + (size_t)n * 16 + c * 4);
  float acc[16];
#pragma unroll
  for (int j = 0; j < 16; ++j) acc[j] = 0.f;
#pragma unroll
  for (int k = 0; k < 16; ++k) {
    const float* wrow = W + k * 16;
#pragma unroll
    for (int j = 0; j < 16; ++j) acc[j] = fmaf(xr[k], wrow[j], acc[j]);
  }
  float s = 0.f, d = 0.f;
#pragma unroll
  for (int j = 0; j < 16; ++j) {
    s = fmaf(acc[j], a_s[j], s);
    d = fmaf(acc[j], a_d[j], d);
  }
  union { __half2 h2[8]; uint4 u4[2]; } pk;
#pragma unroll
  for (int c = 0; c < 8; ++c) pk.h2[c] = __floats2half2_rn(acc[2 * c], acc[2 * c + 1]);
  *(uint4*)(h + (size_t)n * 16)     = pk.u4[0];
  *(uint4*)(h + (size_t)n * 16 + 8) = pk.u4[1];
  asv[n] = s;
  adv[n] = d;
}

// ---------------- per-dst softmax-aggregate: 16 lanes/node, fp16 h gather ----------------
__global__ __launch_bounds__(256) void k_agg(const __half* __restrict__ hh,
    const float* __restrict__ asv, const float* __restrict__ adv,
    const int* __restrict__ offs2, const int* __restrict__ csr2,
    const float* __restrict__ bias, int N, float* __restrict__ out) {
  int t = threadIdx.x;
  int lane = t & 15;
  int n = blockIdx.x * 16 + (t >> 4);
  if (n >= N) return;
  int i0 = offs2[n], i1 = offs2[n + 1];
  float adn = adv[n];
  float z = 0.f, acc = 0.f;
  int i = i0;
  for (; i + 4 <= i1; i += 4) {
    int s0 = csr2[i], s1 = csr2[i + 1], s2 = csr2[i + 2], s3 = csr2[i + 3];
    float a0 = asv[s0], a1 = asv[s1], a2 = asv[s2], a3 = asv[s3];
    float h0 = __half2float(hh[(size_t)s0 * 16 + lane]);
    float h1 = __half2float(hh[(size_t)s1 * 16 + lane]);
    float h2 = __half2float(hh[(size_t)s2 * 16 + lane]);
    float h3 = __half2float(hh[(size_t)s3 * 16 + lane]);
    float e0 = __expf(leaky(a0 + adn));
    float e1 = __expf(leaky(a1 + adn));
    float e2 = __expf(leaky(a2 + adn));
    float e3 = __expf(leaky(a3 + adn));
    z += (e0 + e1) + (e2 + e3);
    acc = fmaf(e0, h0, acc);
    acc = fmaf(e1, h1, acc);
    acc = fmaf(e2, h2, acc);
    acc = fmaf(e3, h3, acc);
  }
  for (; i < i1; ++i) {
    int s = csr2[i];
    float e = __expf(leaky(asv[s] + adn));
    z += e;
    acc = fmaf(e, __half2float(hh[(size_t)s * 16 + lane]), acc);
  }
  out[(size_t)n * 16 + lane] = fmaxf(acc / z + bias[lane], 0.f);
}

// logits = g @ Wout + bout, row-softmax
__global__ void k_out(const float* __restrict__ g, const float* __restrict__ Wout,
                      const float* __restrict__ bout, int N, float* __restrict__ out) {
  int n = blockIdx.x * blockDim.x + threadIdx.x;
  if (n >= N) return;
  float xr[16];
#pragma unroll
  for (int c = 0; c < 4; ++c) ((float4*)xr)[c] = *(const float4*)(g + (size_t)n * 16 + c * 4);
  float lg[16];
#pragma unroll
  for (int c = 0; c < 16; ++c) lg[c] = bout[c];
#pragma unroll
  for (int k = 0; k < 16; ++k) {
    const float* wrow = Wout + k * 16;
#pragma unroll
    for (int c = 0; c < 16; ++c) lg[c] = fmaf(xr[k], wrow[c], lg[c]);
  }
  float m = lg[0];
#pragma unroll
  for (int c = 1; c < 16; ++c) m = fmaxf(m, lg[c]);
  float e[16];
  float zs = 0.f;
#pragma unroll
  for (int c = 0; c < 16; ++c) { e[c] = __expf(lg[c] - m); zs += e[c]; }
  float inv = 1.f / zs;
  float4* op = (float4*)(out + (size_t)n * 16);
  op[0] = make_float4(e[0] * inv, e[1] * inv, e[2] * inv, e[3] * inv);
  op[1] = make_float4(e[4] * inv, e[5] * inv, e[6] * inv, e[7] * inv);
  op[2] = make_float4(e[8] * inv, e[9] * inv, e[10] * inv, e[11] * inv);
  op[3] = make_float4(e[12] * inv, e[13] * inv, e[14] * inv, e[15] * inv);
}

// ---------------- launch ----------------

extern "C" void kernel_launch(void* const* d_in, const int* in_sizes, int n_in,
                              void* d_out, int out_size, void* d_ws, size_t ws_size,
                              hipStream_t stream) {
  const float* x    = (const float*)d_in[0];
  const float* W1   = (const float*)d_in[1];
  const float* as1  = (const float*)d_in[2];
  const float* ad1  = (const float*)d_in[3];
  const float* b1   = (const float*)d_in[4];
  const float* W2   = (const float*)d_in[5];
  const float* as2  = (const float*)d_in[6];
  const float* ad2  = (const float*)d_in[7];
  const float* b2   = (const float*)d_in[8];
  const float* Wout = (const float*)d_in[9];
  const float* bout = (const float*)d_in[10];
  const int*   ei   = (const int*)d_in[11];

  const int N  = in_sizes[0] / 512;
  const int E  = in_sizes[11] / 2;
  const int ET = E + N;
  const int B  = (N + BK - 1) >> BK_SHIFT;
  float* out = (float*)d_out;

  char* w = (char*)d_ws;
  auto alloc = [&](size_t bytes) {
    char* p = w;
    w += (bytes + 255) & ~(size_t)255;
    return p;
  };
  __half* h1  = (__half*)alloc((size_t)N * 16 * 2);
  __half* h2  = (__half*)alloc((size_t)N * 16 * 2);
  float* x2   = (float*)alloc((size_t)N * 16 * 4);
  float* g    = (float*)alloc((size_t)N * 16 * 4);
  float* asv1 = (float*)alloc((size_t)N * 4);
  float* adv1 = (float*)alloc((size_t)N * 4);
  float* asv2 = (float*)alloc((size_t)N * 4);
  float* adv2 = (float*)alloc((size_t)N * 4);
  int* ghist = (int*)alloc((size_t)B * 4);
  int* offs  = (int*)alloc((size_t)B * 4);
  int* gcur  = (int*)alloc((size_t)B * 4);
  unsigned int* grec = (unsigned int*)alloc((size_t)ET * 4);
  int* csr2  = (int*)alloc((size_t)ET * 4);
  int* offs2 = (int*)alloc((size_t)(N + 1) * 4);

  const int NB256 = (N + 255) / 256;
  const int NB64  = (N + 63) / 64;
  const int nScat = (ET + CH - 1) / CH;

  // bucket build + within-bucket sort -> per-dst CSR
  hipMemsetAsync(ghist, 0, (size_t)B * 4, stream);
  k_hist<<<nScat, 256, 0, stream>>>(ei, E, ET, B, ghist);
  k_scanbk<<<1, 256, 0, stream>>>(ghist, B, offs, gcur);
  k_scatter<<<nScat, 256, 0, stream>>>(ei, E, ET, B, gcur, grec);
  k_sortbk<<<B, 256, 0, stream>>>(grec, offs, ghist, N, B, ET, csr2, offs2);

  // layer 1
  k_gemm1<<<NB64, 256, 0, stream>>>(x, W1, as1, ad1, N, h1, asv1, adv1);
  k_agg<<<(N + 15) / 16, 256, 0, stream>>>(h1, asv1, adv1, offs2, csr2, b1, N, x2);

  // layer 2
  k_gemm16<<<NB256, 256, 0, stream>>>(x2, W2, as2, ad2, N, h2, asv2, adv2);
  k_agg<<<(N + 15) / 16, 256, 0, stream>>>(h2, asv2, adv2, offs2, csr2, b2, N, g);

  // output head
  k_out<<<NB256, 256, 0, stream>>>(g, Wout, bout, N, out);
}

// Round 6
// 257.314 us; speedup vs baseline: 1.3373x; 1.3373x over previous
//
#include <hip/hip_runtime.h>
#include <hip/hip_fp16.h>

#define NEG_SLOPE 0.2f
#define BK 128            // dst nodes per bucket
#define BK_SHIFT 7
#define CH 8192           // edges per scatter workgroup
#define BMAX 1024         // max buckets (N<=131072)

__device__ __forceinline__ float leaky(float v) { return v > 0.f ? v : NEG_SLOPE * v; }

// ---------------- phase A: global bucket histogram ----------------
__global__ __launch_bounds__(256) void k_hist(const int* __restrict__ ei, int E, int ET,
                                              int B, int* __restrict__ ghist) {
  __shared__ int hist[BMAX];
  int t = threadIdx.x;
  for (int i = t; i < B; i += 256) hist[i] = 0;
  __syncthreads();
  int cbase = blockIdx.x * CH;
  int lim = min(CH, ET - cbase);
  for (int k = t; k < lim; k += 256) {
    int e = cbase + k;
    int d = (e < E) ? ei[E + e] : (e - E);   // self-loops appended
    atomicAdd(&hist[d >> BK_SHIFT], 1);
  }
  __syncthreads();
  for (int i = t; i < B; i += 256)
    if (hist[i]) atomicAdd(&ghist[i], hist[i]);
}

// ---------------- phase B: scan bucket counts -> offsets + cursors ----------------
__global__ __launch_bounds__(256) void k_scanbk(const int* __restrict__ ghist, int B,
                                                int* __restrict__ offs, int* __restrict__ gcur) {
  __shared__ int part[256];
  __shared__ int vals[BMAX];
  int t = threadIdx.x;
  int b4 = t * 4, s = 0;
  for (int i = 0; i < 4; ++i) {
    int idx = b4 + i;
    int v = (idx < B) ? ghist[idx] : 0;
    vals[idx] = v; s += v;
  }
  part[t] = s;
  __syncthreads();
  for (int d = 1; d < 256; d <<= 1) {
    int tv = (t >= d) ? part[t - d] : 0;
    __syncthreads();
    part[t] += tv;
    __syncthreads();
  }
  int run = part[t] - s;   // exclusive prefix of this thread's 4 buckets
  for (int i = 0; i < 4; ++i) {
    int idx = b4 + i;
    if (idx < B) { offs[idx] = run; gcur[idx] = run; }
    run += vals[idx];
  }
}

// ---------------- phase C: LDS-binned scatter (coalesced runs) ----------------
__global__ __launch_bounds__(256) void k_scatter(const int* __restrict__ ei, int E, int ET,
                                                 int B, int* __restrict__ gcur,
                                                 unsigned int* __restrict__ grec) {
  __shared__ int hist[BMAX];
  __shared__ int base[BMAX];
  __shared__ int cur[BMAX];
  __shared__ int gb[BMAX];
  __shared__ int part[256];
  __shared__ unsigned int recs[CH];
  __shared__ unsigned short bOf[CH];
  int t = threadIdx.x;
  for (int i = t; i < B; i += 256) hist[i] = 0;
  __syncthreads();
  int cbase = blockIdx.x * CH;
  int lim = min(CH, ET - cbase);
  // pass 1: local counts
  for (int k = t; k < lim; k += 256) {
    int e = cbase + k;
    int d = (e < E) ? ei[E + e] : (e - E);
    atomicAdd(&hist[d >> BK_SHIFT], 1);
  }
  __syncthreads();
  // scan hist -> base (exclusive), cur = base
  {
    int b4 = t * 4, s = 0;
    int v0 = 0, v1 = 0, v2 = 0, v3 = 0;
    if (b4 + 0 < B) v0 = hist[b4 + 0];
    if (b4 + 1 < B) v1 = hist[b4 + 1];
    if (b4 + 2 < B) v2 = hist[b4 + 2];
    if (b4 + 3 < B) v3 = hist[b4 + 3];
    s = v0 + v1 + v2 + v3;
    part[t] = s;
    __syncthreads();
    for (int d = 1; d < 256; d <<= 1) {
      int tv = (t >= d) ? part[t - d] : 0;
      __syncthreads();
      part[t] += tv;
      __syncthreads();
    }
    int run = part[t] - s;
    if (b4 + 0 < B) { base[b4 + 0] = run; cur[b4 + 0] = run; } run += v0;
    if (b4 + 1 < B) { base[b4 + 1] = run; cur[b4 + 1] = run; } run += v1;
    if (b4 + 2 < B) { base[b4 + 2] = run; cur[b4 + 2] = run; } run += v2;
    if (b4 + 3 < B) { base[b4 + 3] = run; cur[b4 + 3] = run; } run += v3;
  }
  __syncthreads();
  // pass 2: place records into LDS grouped by bucket
  for (int k = t; k < lim; k += 256) {
    int e = cbase + k;
    int s, d;
    if (e < E) { s = ei[e]; d = ei[E + e]; }
    else       { s = e - E; d = s; }
    int b = d >> BK_SHIFT;
    int r = atomicAdd(&cur[b], 1);
    recs[r] = (unsigned)s | ((unsigned)(d & (BK - 1)) << 17);
    bOf[r] = (unsigned short)b;
  }
  __syncthreads();
  // reserve contiguous global regions per bucket
  for (int i = t; i < B; i += 256) {
    int cnt = cur[i] - base[i];
    gb[i] = cnt ? atomicAdd(&gcur[i], cnt) : 0;
  }
  __syncthreads();
  // flush: consecutive LDS slots in a bucket -> consecutive global addresses
  for (int p = t; p < lim; p += 256) {
    int b = bOf[p];
    grec[gb[b] + (p - base[b])] = recs[p];
  }
}

// ---------------- phase D: within-bucket counting sort -> per-dst CSR ----------------
__global__ __launch_bounds__(256) void k_sortbk(const unsigned int* __restrict__ grec,
    const int* __restrict__ offs, const int* __restrict__ ghist,
    int N, int B, int ET, int* __restrict__ csr2, int* __restrict__ offs2) {
  __shared__ int hist[BK];
  __shared__ int cur[BK];
  __shared__ int sc[BK];
  int b = blockIdx.x;
  int t = threadIdx.x;
  if (t < BK) hist[t] = 0;
  __syncthreads();
  int i0 = offs[b], cnt = ghist[b];
  for (int i = t; i < cnt; i += 256) atomicAdd(&hist[grec[i0 + i] >> 17], 1);
  __syncthreads();
  if (t < BK) sc[t] = hist[t];
  __syncthreads();
  for (int d = 1; d < BK; d <<= 1) {
    int v = (t >= d && t < BK) ? sc[t - d] : 0;
    __syncthreads();
    if (t < BK) sc[t] += v;
    __syncthreads();
  }
  if (t < BK) {
    int excl = sc[t] - hist[t];
    cur[t] = excl;
    int n = (b << BK_SHIFT) + t;
    if (n < N) offs2[n] = i0 + excl;
  }
  if (b == 0 && t == 0) offs2[N] = ET;
  __syncthreads();
  for (int i = t; i < cnt; i += 256) {
    unsigned r = grec[i0 + i];
    int dl = r >> 17;
    int p = atomicAdd(&cur[dl], 1);
    csr2[i0 + p] = r & 0x1FFFF;
  }
}

// ---------------- layer math ----------------

// FMA one 32-k chunk (8 float4) against W1 rows (wave-uniform addresses).
__device__ __forceinline__ void fma_chunk(const float* __restrict__ W1, int c,
                                          const float4* buf, float* acc) {
#pragma unroll
  for (int u = 0; u < 8; ++u) {
    float xq[4] = {buf[u].x, buf[u].y, buf[u].z, buf[u].w};
#pragma unroll
    for (int q = 0; q < 4; ++q) {
      const float* wrow = W1 + (size_t)(c * 32 + u * 4 + q) * 16;  // uniform
#pragma unroll
      for (int j = 0; j < 16; ++j) acc[j] = fmaf(xq[q], wrow[j], acc[j]);
    }
  }
}

// h = x @ W1 (512 -> 16) as fp16, plus alpha_s/alpha_d (f32).
// One node per thread, direct float4 streaming, 2-deep double-buffered loads.
__global__ __launch_bounds__(256) void k_gemm1(
    const float* __restrict__ x, const float* __restrict__ W1,
    const float* __restrict__ a_s, const float* __restrict__ a_d,
    int N, __half* __restrict__ h, float* __restrict__ asv, float* __restrict__ adv) {
  const int node = blockIdx.x * 256 + threadIdx.x;
  if (node >= N) return;
  const float4* xr = (const float4*)(x + (size_t)node * 512);

  float acc[16];
#pragma unroll
  for (int j = 0; j < 16; ++j) acc[j] = 0.f;

  float4 A[8], Bv[8];
#pragma unroll
  for (int u = 0; u < 8; ++u) A[u] = xr[u];            // chunk 0

#pragma unroll
  for (int p = 0; p < 8; ++p) {                        // chunks 2p, 2p+1
#pragma unroll
    for (int u = 0; u < 8; ++u) Bv[u] = xr[(2 * p + 1) * 8 + u];
    fma_chunk(W1, 2 * p, A, acc);
    if (p < 7) {
#pragma unroll
      for (int u = 0; u < 8; ++u) A[u] = xr[(2 * p + 2) * 8 + u];
    }
    fma_chunk(W1, 2 * p + 1, Bv, acc);
  }

  float s = 0.f, d = 0.f;
#pragma unroll
  for (int j = 0; j < 16; ++j) {
    s = fmaf(acc[j], a_s[j], s);
    d = fmaf(acc[j], a_d[j], d);
  }
  union { __half2 h2[8]; uint4 u4[2]; } pk;
#pragma unroll
  for (int c = 0; c < 8; ++c) pk.h2[c] = __floats2half2_rn(acc[2 * c], acc[2 * c + 1]);
  *(uint4*)(h + (size_t)node * 16)     = pk.u4[0];
  *(uint4*)(h + (size_t)node * 16 + 8) = pk.u4[1];
  asv[node] = s;
  adv[node] = d;
}

// h = xin @ W (16 -> 16) as fp16, plus alpha_s/alpha_d (f32).
__global__ void k_gemm16(const float* __restrict__ xin, const float* __restrict__ W,
                         const float* __restrict__ a_s, const float* __restrict__ a_d,
                         int N, __half* __restrict__ h, float* __restrict__ asv,
                         float* __restrict__ adv) {
  int n = blockIdx.x * blockDim.x + threadIdx.x;
  if (n >= N) return;
  float xr[16];
#pragma unroll
  for (int c = 0; c < 4; ++c) ((float4*)xr)[c] = *(const float4*)(xin + (size_t)n * 16 + c * 4);
  float acc[16];
#pragma unroll
  for (int j = 0; j < 16; ++j) acc[j] = 0.f;
#pragma unroll
  for (int k = 0; k < 16; ++k) {
    const float* wrow = W + k * 16;
#pragma unroll
    for (int j = 0; j < 16; ++j) acc[j] = fmaf(xr[k], wrow[j], acc[j]);
  }
  float s = 0.f, d = 0.f;
#pragma unroll
  for (int j = 0; j < 16; ++j) {
    s = fmaf(acc[j], a_s[j], s);
    d = fmaf(acc[j], a_d[j], d);
  }
  union { __half2 h2[8]; uint4 u4[2]; } pk;
#pragma unroll
  for (int c = 0; c < 8; ++c) pk.h2[c] = __floats2half2_rn(acc[2 * c], acc[2 * c + 1]);
  *(uint4*)(h + (size_t)n * 16)     = pk.u4[0];
  *(uint4*)(h + (size_t)n * 16 + 8) = pk.u4[1];
  asv[n] = s;
  adv[n] = d;
}

// ---------------- per-dst softmax-aggregate: 16 lanes/node, fp16 h gather ----------------
__global__ __launch_bounds__(256) void k_agg(const __half* __restrict__ hh,
    const float* __restrict__ asv, const float* __restrict__ adv,
    const int* __restrict__ offs2, const int* __restrict__ csr2,
    const float* __restrict__ bias, int N, float* __restrict__ out) {
  int t = threadIdx.x;
  int lane = t & 15;
  int n = blockIdx.x * 16 + (t >> 4);
  if (n >= N) return;
  int i0 = offs2[n], i1 = offs2[n + 1];
  float adn = adv[n];
  float z = 0.f, acc = 0.f;
  int i = i0;
  for (; i + 4 <= i1; i += 4) {
    int s0 = csr2[i], s1 = csr2[i + 1], s2 = csr2[i + 2], s3 = csr2[i + 3];
    float a0 = asv[s0], a1 = asv[s1], a2 = asv[s2], a3 = asv[s3];
    float h0 = __half2float(hh[(size_t)s0 * 16 + lane]);
    float h1 = __half2float(hh[(size_t)s1 * 16 + lane]);
    float h2 = __half2float(hh[(size_t)s2 * 16 + lane]);
    float h3 = __half2float(hh[(size_t)s3 * 16 + lane]);
    float e0 = __expf(leaky(a0 + adn));
    float e1 = __expf(leaky(a1 + adn));
    float e2 = __expf(leaky(a2 + adn));
    float e3 = __expf(leaky(a3 + adn));
    z += (e0 + e1) + (e2 + e3);
    acc = fmaf(e0, h0, acc);
    acc = fmaf(e1, h1, acc);
    acc = fmaf(e2, h2, acc);
    acc = fmaf(e3, h3, acc);
  }
  for (; i < i1; ++i) {
    int s = csr2[i];
    float e = __expf(leaky(asv[s] + adn));
    z += e;
    acc = fmaf(e, __half2float(hh[(size_t)s * 16 + lane]), acc);
  }
  out[(size_t)n * 16 + lane] = fmaxf(acc / z + bias[lane], 0.f);
}

// logits = g @ Wout + bout, row-softmax
__global__ void k_out(const float* __restrict__ g, const float* __restrict__ Wout,
                      const float* __restrict__ bout, int N, float* __restrict__ out) {
  int n = blockIdx.x * blockDim.x + threadIdx.x;
  if (n >= N) return;
  float xr[16];
#pragma unroll
  for (int c = 0; c < 4; ++c) ((float4*)xr)[c] = *(const float4*)(g + (size_t)n * 16 + c * 4);
  float lg[16];
#pragma unroll
  for (int c = 0; c < 16; ++c) lg[c] = bout[c];
#pragma unroll
  for (int k = 0; k < 16; ++k) {
    const float* wrow = Wout + k * 16;
#pragma unroll
    for (int c = 0; c < 16; ++c) lg[c] = fmaf(xr[k], wrow[c], lg[c]);
  }
  float m = lg[0];
#pragma unroll
  for (int c = 1; c < 16; ++c) m = fmaxf(m, lg[c]);
  float e[16];
  float zs = 0.f;
#pragma unroll
  for (int c = 0; c < 16; ++c) { e[c] = __expf(lg[c] - m); zs += e[c]; }
  float inv = 1.f / zs;
  float4* op = (float4*)(out + (size_t)n * 16);
  op[0] = make_float4(e[0] * inv, e[1] * inv, e[2] * inv, e[3] * inv);
  op[1] = make_float4(e[4] * inv, e[5] * inv, e[6] * inv, e[7] * inv);
  op[2] = make_float4(e[8] * inv, e[9] * inv, e[10] * inv, e[11] * inv);
  op[3] = make_float4(e[12] * inv, e[13] * inv, e[14] * inv, e[15] * inv);
}

// ---------------- launch ----------------

extern "C" void kernel_launch(void* const* d_in, const int* in_sizes, int n_in,
                              void* d_out, int out_size, void* d_ws, size_t ws_size,
                              hipStream_t stream) {
  const float* x    = (const float*)d_in[0];
  const float* W1   = (const float*)d_in[1];
  const float* as1  = (const float*)d_in[2];
  const float* ad1  = (const float*)d_in[3];
  const float* b1   = (const float*)d_in[4];
  const float* W2   = (const float*)d_in[5];
  const float* as2  = (const float*)d_in[6];
  const float* ad2  = (const float*)d_in[7];
  const float* b2   = (const float*)d_in[8];
  const float* Wout = (const float*)d_in[9];
  const float* bout = (const float*)d_in[10];
  const int*   ei   = (const int*)d_in[11];

  const int N  = in_sizes[0] / 512;
  const int E  = in_sizes[11] / 2;
  const int ET = E + N;
  const int B  = (N + BK - 1) >> BK_SHIFT;
  float* out = (float*)d_out;

  char* w = (char*)d_ws;
  auto alloc = [&](size_t bytes) {
    char* p = w;
    w += (bytes + 255) & ~(size_t)255;
    return p;
  };
  __half* h1  = (__half*)alloc((size_t)N * 16 * 2);
  __half* h2  = (__half*)alloc((size_t)N * 16 * 2);
  float* x2   = (float*)alloc((size_t)N * 16 * 4);
  float* g    = (float*)alloc((size_t)N * 16 * 4);
  float* asv1 = (float*)alloc((size_t)N * 4);
  float* adv1 = (float*)alloc((size_t)N * 4);
  float* asv2 = (float*)alloc((size_t)N * 4);
  float* adv2 = (float*)alloc((size_t)N * 4);
  int* ghist = (int*)alloc((size_t)B * 4);
  int* offs  = (int*)alloc((size_t)B * 4);
  int* gcur  = (int*)alloc((size_t)B * 4);
  unsigned int* grec = (unsigned int*)alloc((size_t)ET * 4);
  int* csr2  = (int*)alloc((size_t)ET * 4);
  int* offs2 = (int*)alloc((size_t)(N + 1) * 4);

  const int NB256 = (N + 255) / 256;
  const int nScat = (ET + CH - 1) / CH;

  // bucket build + within-bucket sort -> per-dst CSR
  hipMemsetAsync(ghist, 0, (size_t)B * 4, stream);
  k_hist<<<nScat, 256, 0, stream>>>(ei, E, ET, B, ghist);
  k_scanbk<<<1, 256, 0, stream>>>(ghist, B, offs, gcur);
  k_scatter<<<nScat, 256, 0, stream>>>(ei, E, ET, B, gcur, grec);
  k_sortbk<<<B, 256, 0, stream>>>(grec, offs, ghist, N, B, ET, csr2, offs2);

  // layer 1
  k_gemm1<<<NB256, 256, 0, stream>>>(x, W1, as1, ad1, N, h1, asv1, adv1);
  k_agg<<<(N + 15) / 16, 256, 0, stream>>>(h1, asv1, adv1, offs2, csr2, b1, N, x2);

  // layer 2
  k_gemm16<<<NB256, 256, 0, stream>>>(x2, W2, as2, ad2, N, h2, asv2, adv2);
  k_agg<<<(N + 15) / 16, 256, 0, stream>>>(h2, asv2, adv2, offs2, csr2, b2, N, g);

  // output head
  k_out<<<NB256, 256, 0, stream>>>(g, Wout, bout, N, out);
}

// Round 7
// 245.331 us; speedup vs baseline: 1.4026x; 1.0488x over previous
//
#include <hip/hip_runtime.h>
#include <hip/hip_fp16.h>

#define NEG_SLOPE 0.2f
#define BK 128            // dst nodes per bucket
#define BK_SHIFT 7
#define CH 8192           // edges per scatter workgroup
#define BMAX 1024         // max buckets (N<=131072)

__device__ __forceinline__ float leaky(float v) { return v > 0.f ? v : NEG_SLOPE * v; }

// ---------------- phase A: global bucket histogram ----------------
__global__ __launch_bounds__(256) void k_hist(const int* __restrict__ ei, int E, int ET,
                                              int B, int* __restrict__ ghist) {
  __shared__ int hist[BMAX];
  int t = threadIdx.x;
  for (int i = t; i < B; i += 256) hist[i] = 0;
  __syncthreads();
  int cbase = blockIdx.x * CH;
  int lim = min(CH, ET - cbase);
  for (int k = t; k < lim; k += 256) {
    int e = cbase + k;
    int d = (e < E) ? ei[E + e] : (e - E);   // self-loops appended
    atomicAdd(&hist[d >> BK_SHIFT], 1);
  }
  __syncthreads();
  for (int i = t; i < B; i += 256)
    if (hist[i]) atomicAdd(&ghist[i], hist[i]);
}

// ---------------- phase B: scan bucket counts -> offsets + cursors ----------------
__global__ __launch_bounds__(256) void k_scanbk(const int* __restrict__ ghist, int B,
                                                int* __restrict__ offs, int* __restrict__ gcur) {
  __shared__ int part[256];
  __shared__ int vals[BMAX];
  int t = threadIdx.x;
  int b4 = t * 4, s = 0;
  for (int i = 0; i < 4; ++i) {
    int idx = b4 + i;
    int v = (idx < B) ? ghist[idx] : 0;
    vals[idx] = v; s += v;
  }
  part[t] = s;
  __syncthreads();
  for (int d = 1; d < 256; d <<= 1) {
    int tv = (t >= d) ? part[t - d] : 0;
    __syncthreads();
    part[t] += tv;
    __syncthreads();
  }
  int run = part[t] - s;   // exclusive prefix of this thread's 4 buckets
  for (int i = 0; i < 4; ++i) {
    int idx = b4 + i;
    if (idx < B) { offs[idx] = run; gcur[idx] = run; }
    run += vals[idx];
  }
}

// ---------------- phase C: LDS-binned scatter (coalesced runs) ----------------
__global__ __launch_bounds__(256) void k_scatter(const int* __restrict__ ei, int E, int ET,
                                                 int B, int* __restrict__ gcur,
                                                 unsigned int* __restrict__ grec) {
  __shared__ int hist[BMAX];
  __shared__ int base[BMAX];
  __shared__ int cur[BMAX];
  __shared__ int gb[BMAX];
  __shared__ int part[256];
  __shared__ unsigned int recs[CH];
  __shared__ unsigned short bOf[CH];
  int t = threadIdx.x;
  for (int i = t; i < B; i += 256) hist[i] = 0;
  __syncthreads();
  int cbase = blockIdx.x * CH;
  int lim = min(CH, ET - cbase);
  // pass 1: local counts
  for (int k = t; k < lim; k += 256) {
    int e = cbase + k;
    int d = (e < E) ? ei[E + e] : (e - E);
    atomicAdd(&hist[d >> BK_SHIFT], 1);
  }
  __syncthreads();
  // scan hist -> base (exclusive), cur = base
  {
    int b4 = t * 4, s = 0;
    int v0 = 0, v1 = 0, v2 = 0, v3 = 0;
    if (b4 + 0 < B) v0 = hist[b4 + 0];
    if (b4 + 1 < B) v1 = hist[b4 + 1];
    if (b4 + 2 < B) v2 = hist[b4 + 2];
    if (b4 + 3 < B) v3 = hist[b4 + 3];
    s = v0 + v1 + v2 + v3;
    part[t] = s;
    __syncthreads();
    for (int d = 1; d < 256; d <<= 1) {
      int tv = (t >= d) ? part[t - d] : 0;
      __syncthreads();
      part[t] += tv;
      __syncthreads();
    }
    int run = part[t] - s;
    if (b4 + 0 < B) { base[b4 + 0] = run; cur[b4 + 0] = run; } run += v0;
    if (b4 + 1 < B) { base[b4 + 1] = run; cur[b4 + 1] = run; } run += v1;
    if (b4 + 2 < B) { base[b4 + 2] = run; cur[b4 + 2] = run; } run += v2;
    if (b4 + 3 < B) { base[b4 + 3] = run; cur[b4 + 3] = run; } run += v3;
  }
  __syncthreads();
  // pass 2: place records into LDS grouped by bucket
  for (int k = t; k < lim; k += 256) {
    int e = cbase + k;
    int s, d;
    if (e < E) { s = ei[e]; d = ei[E + e]; }
    else       { s = e - E; d = s; }
    int b = d >> BK_SHIFT;
    int r = atomicAdd(&cur[b], 1);
    recs[r] = (unsigned)s | ((unsigned)(d & (BK - 1)) << 17);
    bOf[r] = (unsigned short)b;
  }
  __syncthreads();
  // reserve contiguous global regions per bucket
  for (int i = t; i < B; i += 256) {
    int cnt = cur[i] - base[i];
    gb[i] = cnt ? atomicAdd(&gcur[i], cnt) : 0;
  }
  __syncthreads();
  // flush: consecutive LDS slots in a bucket -> consecutive global addresses
  for (int p = t; p < lim; p += 256) {
    int b = bOf[p];
    grec[gb[b] + (p - base[b])] = recs[p];
  }
}

// ---------------- phase D: within-bucket counting sort -> per-dst CSR ----------------
__global__ __launch_bounds__(256) void k_sortbk(const unsigned int* __restrict__ grec,
    const int* __restrict__ offs, const int* __restrict__ ghist,
    int N, int B, int ET, int* __restrict__ csr2, int* __restrict__ offs2) {
  __shared__ int hist[BK];
  __shared__ int cur[BK];
  __shared__ int sc[BK];
  int b = blockIdx.x;
  int t = threadIdx.x;
  if (t < BK) hist[t] = 0;
  __syncthreads();
  int i0 = offs[b], cnt = ghist[b];
  for (int i = t; i < cnt; i += 256) atomicAdd(&hist[grec[i0 + i] >> 17], 1);
  __syncthreads();
  if (t < BK) sc[t] = hist[t];
  __syncthreads();
  for (int d = 1; d < BK; d <<= 1) {
    int v = (t >= d && t < BK) ? sc[t - d] : 0;
    __syncthreads();
    if (t < BK) sc[t] += v;
    __syncthreads();
  }
  if (t < BK) {
    int excl = sc[t] - hist[t];
    cur[t] = excl;
    int n = (b << BK_SHIFT) + t;
    if (n < N) offs2[n] = i0 + excl;
  }
  if (b == 0 && t == 0) offs2[N] = ET;
  __syncthreads();
  for (int i = t; i < cnt; i += 256) {
    unsigned r = grec[i0 + i];
    int dl = r >> 17;
    int p = atomicAdd(&cur[dl], 1);
    csr2[i0 + p] = r & 0x1FFFF;
  }
}

// ---------------- layer math ----------------

// h = x @ W1 (512 -> 16) as fp16, plus alpha_s/alpha_d (f32).
// 256 thr = 4 waves; wave w stages (global_load_lds, XOR-swizzled via pre-swizzled
// global source) exactly the 64 rows its own lanes consume -> NO barriers.
// Double-buffered chunks of 32 k-values, counted s_waitcnt vmcnt(8).
__global__ __launch_bounds__(256) void k_gemm1(
    const float* __restrict__ x, const float* __restrict__ W1,
    const float* __restrict__ a_s, const float* __restrict__ a_d,
    int N, __half* __restrict__ h, float* __restrict__ asv, float* __restrict__ adv) {
  __shared__ float xs[2][256 * 32];         // 2 x 32 KB
  const int tid = threadIdx.x;
  const int w = tid >> 6;                   // wave id (uniform per wave)
  const int l = tid & 63;                   // lane
  const int nbase = blockIdx.x * 256;
  const int node = nbase + tid;

  // staging geometry: wave w, segment s_ (0..7): lane l covers
  //   row  = w*64 + s_*8 + (l>>3)   (row&7 == l>>3)
  //   phys slot (l&7) holds logical float4 (l&7)^(row&7)  -> pre-swizzled source
  const int rb = w * 64 + (l >> 3);
  const int cswz = ((l & 7) ^ (l >> 3)) * 4;     // float offset within 32-f chunk
  char* ldsb = (char*)&xs[0][0];

#define STAGE(chunk, buf) do {                                                   \
    _Pragma("unroll")                                                            \
    for (int s_ = 0; s_ < 8; ++s_) {                                             \
      int gr = nbase + rb + s_ * 8;                                              \
      if (gr >= N) gr = N - 1;                                                   \
      const float* src_ = x + (size_t)gr * 512 + (chunk) * 32 + cswz;            \
      unsigned off_ = (unsigned)((buf) * 32768 + w * 8192 + s_ * 1024);          \
      off_ = __builtin_amdgcn_readfirstlane(off_);                               \
      __builtin_amdgcn_global_load_lds(                                          \
          (const __attribute__((address_space(1))) void*)src_,                   \
          (__attribute__((address_space(3))) void*)(ldsb + off_), 16, 0, 0);     \
    }                                                                            \
  } while (0)

  float acc[16];
#pragma unroll
  for (int j = 0; j < 16; ++j) acc[j] = 0.f;
  const int sw = tid & 7;                   // row&7 for this thread's row

#define COMPUTE(chunk, buf) do {                                                 \
    const float* rowp_ = &xs[buf][(size_t)tid * 32];                             \
    _Pragma("unroll")                                                            \
    for (int c_ = 0; c_ < 8; ++c_) {                                             \
      float4 v_ = *(const float4*)(rowp_ + ((c_ ^ sw) * 4));                     \
      const float* w0_ = W1 + (size_t)((chunk) * 32 + c_ * 4) * 16;              \
      _Pragma("unroll")                                                          \
      for (int j = 0; j < 16; ++j) acc[j] = fmaf(v_.x, w0_[j], acc[j]);          \
      _Pragma("unroll")                                                          \
      for (int j = 0; j < 16; ++j) acc[j] = fmaf(v_.y, w0_[16 + j], acc[j]);     \
      _Pragma("unroll")                                                          \
      for (int j = 0; j < 16; ++j) acc[j] = fmaf(v_.z, w0_[32 + j], acc[j]);     \
      _Pragma("unroll")                                                          \
      for (int j = 0; j < 16; ++j) acc[j] = fmaf(v_.w, w0_[48 + j], acc[j]);     \
    }                                                                            \
  } while (0)

  STAGE(0, 0);
#pragma unroll 1
  for (int ck = 0; ck < 15; ++ck) {
    asm volatile("s_waitcnt lgkmcnt(0)" ::: "memory");   // prior chunk's ds_reads done
    STAGE(ck + 1, (ck + 1) & 1);                         // prefetch next chunk
    asm volatile("s_waitcnt vmcnt(8)" ::: "memory");     // current chunk landed
    COMPUTE(ck, ck & 1);
  }
  asm volatile("s_waitcnt vmcnt(0)" ::: "memory");
  COMPUTE(15, 1);

#undef STAGE
#undef COMPUTE

  if (node < N) {
    float s = 0.f, d = 0.f;
#pragma unroll
    for (int j = 0; j < 16; ++j) {
      s = fmaf(acc[j], a_s[j], s);
      d = fmaf(acc[j], a_d[j], d);
    }
    union { __half2 h2[8]; uint4 u4[2]; } pk;
#pragma unroll
    for (int c = 0; c < 8; ++c) pk.h2[c] = __floats2half2_rn(acc[2 * c], acc[2 * c + 1]);
    *(uint4*)(h + (size_t)node * 16)     = pk.u4[0];
    *(uint4*)(h + (size_t)node * 16 + 8) = pk.u4[1];
    asv[node] = s;
    adv[node] = d;
  }
}

// h = xin @ W (16 -> 16) as fp16, plus alpha_s/alpha_d (f32).
__global__ void k_gemm16(const float* __restrict__ xin, const float* __restrict__ W,
                         const float* __restrict__ a_s, const float* __restrict__ a_d,
                         int N, __half* __restrict__ h, float* __restrict__ asv,
                         float* __restrict__ adv) {
  int n = blockIdx.x * blockDim.x + threadIdx.x;
  if (n >= N) return;
  float xr[16];
#pragma unroll
  for (int c = 0; c < 4; ++c) ((float4*)xr)[c] = *(const float4*)(xin + (size_t)n * 16 + c * 4);
  float acc[16];
#pragma unroll
  for (int j = 0; j < 16; ++j) acc[j] = 0.f;
#pragma unroll
  for (int k = 0; k < 16; ++k) {
    const float* wrow = W + k * 16;
#pragma unroll
    for (int j = 0; j < 16; ++j) acc[j] = fmaf(xr[k], wrow[j], acc[j]);
  }
  float s = 0.f, d = 0.f;
#pragma unroll
  for (int j = 0; j < 16; ++j) {
    s = fmaf(acc[j], a_s[j], s);
    d = fmaf(acc[j], a_d[j], d);
  }
  union { __half2 h2[8]; uint4 u4[2]; } pk;
#pragma unroll
  for (int c = 0; c < 8; ++c) pk.h2[c] = __floats2half2_rn(acc[2 * c], acc[2 * c + 1]);
  *(uint4*)(h + (size_t)n * 16)     = pk.u4[0];
  *(uint4*)(h + (size_t)n * 16 + 8) = pk.u4[1];
  asv[n] = s;
  adv[n] = d;
}

// ---------------- per-dst softmax-aggregate: 16 lanes/node, fp16 h gather ----------------
__global__ __launch_bounds__(256) void k_agg(const __half* __restrict__ hh,
    const float* __restrict__ asv, const float* __restrict__ adv,
    const int* __restrict__ offs2, const int* __restrict__ csr2,
    const float* __restrict__ bias, int N, float* __restrict__ out) {
  int t = threadIdx.x;
  int lane = t & 15;
  int n = blockIdx.x * 16 + (t >> 4);
  if (n >= N) return;
  int i0 = offs2[n], i1 = offs2[n + 1];
  float adn = adv[n];
  float z = 0.f, acc = 0.f;
  int i = i0;
  for (; i + 4 <= i1; i += 4) {
    int s0 = csr2[i], s1 = csr2[i + 1], s2 = csr2[i + 2], s3 = csr2[i + 3];
    float a0 = asv[s0], a1 = asv[s1], a2 = asv[s2], a3 = asv[s3];
    float h0 = __half2float(hh[(size_t)s0 * 16 + lane]);
    float h1 = __half2float(hh[(size_t)s1 * 16 + lane]);
    float h2 = __half2float(hh[(size_t)s2 * 16 + lane]);
    float h3 = __half2float(hh[(size_t)s3 * 16 + lane]);
    float e0 = __expf(leaky(a0 + adn));
    float e1 = __expf(leaky(a1 + adn));
    float e2 = __expf(leaky(a2 + adn));
    float e3 = __expf(leaky(a3 + adn));
    z += (e0 + e1) + (e2 + e3);
    acc = fmaf(e0, h0, acc);
    acc = fmaf(e1, h1, acc);
    acc = fmaf(e2, h2, acc);
    acc = fmaf(e3, h3, acc);
  }
  for (; i < i1; ++i) {
    int s = csr2[i];
    float e = __expf(leaky(asv[s] + adn));
    z += e;
    acc = fmaf(e, __half2float(hh[(size_t)s * 16 + lane]), acc);
  }
  out[(size_t)n * 16 + lane] = fmaxf(acc / z + bias[lane], 0.f);
}

// logits = g @ Wout + bout, row-softmax
__global__ void k_out(const float* __restrict__ g, const float* __restrict__ Wout,
                      const float* __restrict__ bout, int N, float* __restrict__ out) {
  int n = blockIdx.x * blockDim.x + threadIdx.x;
  if (n >= N) return;
  float xr[16];
#pragma unroll
  for (int c = 0; c < 4; ++c) ((float4*)xr)[c] = *(const float4*)(g + (size_t)n * 16 + c * 4);
  float lg[16];
#pragma unroll
  for (int c = 0; c < 16; ++c) lg[c] = bout[c];
#pragma unroll
  for (int k = 0; k < 16; ++k) {
    const float* wrow = Wout + k * 16;
#pragma unroll
    for (int c = 0; c < 16; ++c) lg[c] = fmaf(xr[k], wrow[c], lg[c]);
  }
  float m = lg[0];
#pragma unroll
  for (int c = 1; c < 16; ++c) m = fmaxf(m, lg[c]);
  float e[16];
  float zs = 0.f;
#pragma unroll
  for (int c = 0; c < 16; ++c) { e[c] = __expf(lg[c] - m); zs += e[c]; }
  float inv = 1.f / zs;
  float4* op = (float4*)(out + (size_t)n * 16);
  op[0] = make_float4(e[0] * inv, e[1] * inv, e[2] * inv, e[3] * inv);
  op[1] = make_float4(e[4] * inv, e[5] * inv, e[6] * inv, e[7] * inv);
  op[2] = make_float4(e[8] * inv, e[9] * inv, e[10] * inv, e[11] * inv);
  op[3] = make_float4(e[12] * inv, e[13] * inv, e[14] * inv, e[15] * inv);
}

// ---------------- launch ----------------

extern "C" void kernel_launch(void* const* d_in, const int* in_sizes, int n_in,
                              void* d_out, int out_size, void* d_ws, size_t ws_size,
                              hipStream_t stream) {
  const float* x    = (const float*)d_in[0];
  const float* W1   = (const float*)d_in[1];
  const float* as1  = (const float*)d_in[2];
  const float* ad1  = (const float*)d_in[3];
  const float* b1   = (const float*)d_in[4];
  const float* W2   = (const float*)d_in[5];
  const float* as2  = (const float*)d_in[6];
  const float* ad2  = (const float*)d_in[7];
  const float* b2   = (const float*)d_in[8];
  const float* Wout = (const float*)d_in[9];
  const float* bout = (const float*)d_in[10];
  const int*   ei   = (const int*)d_in[11];

  const int N  = in_sizes[0] / 512;
  const int E  = in_sizes[11] / 2;
  const int ET = E + N;
  const int B  = (N + BK - 1) >> BK_SHIFT;
  float* out = (float*)d_out;

  char* w = (char*)d_ws;
  auto alloc = [&](size_t bytes) {
    char* p = w;
    w += (bytes + 255) & ~(size_t)255;
    return p;
  };
  __half* h1  = (__half*)alloc((size_t)N * 16 * 2);
  __half* h2  = (__half*)alloc((size_t)N * 16 * 2);
  float* x2   = (float*)alloc((size_t)N * 16 * 4);
  float* g    = (float*)alloc((size_t)N * 16 * 4);
  float* asv1 = (float*)alloc((size_t)N * 4);
  float* adv1 = (float*)alloc((size_t)N * 4);
  float* asv2 = (float*)alloc((size_t)N * 4);
  float* adv2 = (float*)alloc((size_t)N * 4);
  int* ghist = (int*)alloc((size_t)B * 4);
  int* offs  = (int*)alloc((size_t)B * 4);
  int* gcur  = (int*)alloc((size_t)B * 4);
  unsigned int* grec = (unsigned int*)alloc((size_t)ET * 4);
  int* csr2  = (int*)alloc((size_t)ET * 4);
  int* offs2 = (int*)alloc((size_t)(N + 1) * 4);

  const int NB256 = (N + 255) / 256;
  const int nScat = (ET + CH - 1) / CH;

  // bucket build + within-bucket sort -> per-dst CSR
  hipMemsetAsync(ghist, 0, (size_t)B * 4, stream);
  k_hist<<<nScat, 256, 0, stream>>>(ei, E, ET, B, ghist);
  k_scanbk<<<1, 256, 0, stream>>>(ghist, B, offs, gcur);
  k_scatter<<<nScat, 256, 0, stream>>>(ei, E, ET, B, gcur, grec);
  k_sortbk<<<B, 256, 0, stream>>>(grec, offs, ghist, N, B, ET, csr2, offs2);

  // layer 1
  k_gemm1<<<NB256, 256, 0, stream>>>(x, W1, as1, ad1, N, h1, asv1, adv1);
  k_agg<<<(N + 15) / 16, 256, 0, stream>>>(h1, asv1, adv1, offs2, csr2, b1, N, x2);

  // layer 2
  k_gemm16<<<NB256, 256, 0, stream>>>(x2, W2, as2, ad2, N, h2, asv2, adv2);
  k_agg<<<(N + 15) / 16, 256, 0, stream>>>(h2, asv2, adv2, offs2, csr2, b2, N, g);

  // output head
  k_out<<<NB256, 256, 0, stream>>>(g, Wout, bout, N, out);
}